// Round 1
// baseline (344.246 us; speedup 1.0000x reference)
//
#include <hip/hip_runtime.h>
#include <stdint.h>

#define B_ 8
#define N_ 8192
#define S_ 2048
#define D_ 256
#define BN_TOT (B_ * N_)   // 65536

typedef __attribute__((ext_vector_type(8))) short bf16x8;
typedef __attribute__((ext_vector_type(4))) float f32x4;

__device__ __forceinline__ float b2f(unsigned short u) {
  union { float f; uint32_t i; } v; v.i = ((uint32_t)u) << 16; return v.f;
}
__device__ __forceinline__ unsigned short f2b(float f) {
  union { float f; uint32_t i; } v; v.f = f;
  uint32_t r = v.i + 0x7FFF + ((v.i >> 16) & 1);
  return (unsigned short)(r >> 16);
}

__device__ __forceinline__ void gload_lds16(const void* g, void* l) {
  __builtin_amdgcn_global_load_lds(
      (const __attribute__((address_space(1))) void*)g,
      (__attribute__((address_space(3))) void*)l, 16, 0, 0);
}

// ---------------- simple f32 -> bf16 cast (weights) ----------------
__global__ __launch_bounds__(256) void cast_f32_bf16(
    const float* __restrict__ in, unsigned short* __restrict__ out, int n) {
  int i = blockIdx.x * 256 + threadIdx.x;
  if (i < n) out[i] = f2b(in[i]);
}

// ------- transpose-cast: f32 [B][256][L] -> bf16 [B][L][ldo] (col 0..255) -------
__global__ __launch_bounds__(256) void transpose_cast(
    const float* __restrict__ in, unsigned short* __restrict__ out,
    int L, int ldo) {
  __shared__ float lds[64][33];
  int c0 = blockIdx.x * 32;
  int r0 = blockIdx.y * 64;
  int b = blockIdx.z;
  int t = threadIdx.x;
  int tx = t & 31, ty = t >> 5;  // ty 0..7
  const float* src = in + ((size_t)b * 256 + r0) * L + c0;
#pragma unroll
  for (int rr = 0; rr < 8; ++rr) {
    int r = ty + rr * 8;
    lds[r][tx] = src[(size_t)r * L + tx];
  }
  __syncthreads();
  int wr = t & 31;   // r-pair
  int wc = t >> 5;   // 0..7
#pragma unroll
  for (int it = 0; it < 4; ++it) {
    int cl = wc + it * 8;
    unsigned short a = f2b(lds[wr * 2][cl]);
    unsigned short b2 = f2b(lds[wr * 2 + 1][cl]);
    uint32_t packed = (uint32_t)a | ((uint32_t)b2 << 16);
    *(uint32_t*)&out[((size_t)b * L + (c0 + cl)) * ldo + r0 + wr * 2] = packed;
  }
}

// ---------------- 3-NN (fp64 ordering) + weights ----------------
__global__ __launch_bounds__(256) void knn_kernel(
    const float* __restrict__ xyz1, const float* __restrict__ xyz2,
    int4* __restrict__ knn_i, float4* __restrict__ knn_w) {
  __shared__ float sx[S_], sy[S_], sz[S_];
  __shared__ double sn2[S_];
  int b = blockIdx.y;
  int t = threadIdx.x;
  const float* x2 = xyz2 + (size_t)b * 3 * S_;
#pragma unroll
  for (int j = 0; j < S_ / 256; ++j) {
    int s = j * 256 + t;
    float x = x2[s], y = x2[S_ + s], z = x2[2 * S_ + s];
    sx[s] = x; sy[s] = y; sz[s] = z;
    sn2[s] = (double)x * x + (double)y * y + (double)z * z;
  }
  __syncthreads();
  int n = blockIdx.x * 256 + t;
  const float* x1 = xyz1 + (size_t)b * 3 * N_;
  double px = x1[n], py = x1[N_ + n], pz = x1[2 * N_ + n];
  double n1 = px * px + py * py + pz * pz;
  double d0 = 1e300, d1 = 1e300, d2 = 1e300;
  int i0 = 0, i1 = 0, i2 = 0;
#pragma unroll 2
  for (int s = 0; s < S_; ++s) {
    double dot = px * sx[s] + py * sy[s] + pz * sz[s];
    double d = n1 + sn2[s] - 2.0 * dot;
    bool c0 = d < d0, c1 = d < d1, c2 = d < d2;
    i2 = c1 ? i1 : (c2 ? s : i2);
    d2 = c1 ? d1 : (c2 ? d : d2);
    i1 = c0 ? i0 : (c1 ? s : i1);
    d1 = c0 ? d0 : (c1 ? d : d1);
    i0 = c0 ? s : i0;
    d0 = c0 ? d : d0;
  }
  float f0 = (float)d0, f1 = (float)d1, f2 = (float)d2;
  float w0 = 1.0f / (f0 + 1e-8f), w1 = 1.0f / (f1 + 1e-8f), w2 = 1.0f / (f2 + 1e-8f);
  float inv = 1.0f / (w0 + w1 + w2);
  int bn = b * N_ + n;
  knn_i[bn] = make_int4(i0, i1, i2, 0);
  knn_w[bn] = make_float4(w0 * inv, w1 * inv, w2 * inv, 0.f);
}

// ---------------- gather-interpolate -> Xcat[:,256:512] ----------------
__global__ __launch_bounds__(256) void interp_kernel(
    const unsigned short* __restrict__ p2t, const int4* __restrict__ knn_i,
    const float4* __restrict__ knn_w, unsigned short* __restrict__ xcat) {
  int wid = threadIdx.x >> 6, lane = threadIdx.x & 63;
  int bn = blockIdx.x * 4 + wid;
  int b = bn >> 13;
  int4 ii = knn_i[bn];
  float4 ww = knn_w[bn];
  int d0 = lane * 4;
  const unsigned short* base = p2t + (size_t)b * S_ * 256;
  ushort4 v0 = *(const ushort4*)(base + (size_t)ii.x * 256 + d0);
  ushort4 v1 = *(const ushort4*)(base + (size_t)ii.y * 256 + d0);
  ushort4 v2 = *(const ushort4*)(base + (size_t)ii.z * 256 + d0);
  float r0 = ww.x * b2f(v0.x) + ww.y * b2f(v1.x) + ww.z * b2f(v2.x);
  float r1 = ww.x * b2f(v0.y) + ww.y * b2f(v1.y) + ww.z * b2f(v2.y);
  float r2 = ww.x * b2f(v0.z) + ww.y * b2f(v1.z) + ww.z * b2f(v2.z);
  float r3 = ww.x * b2f(v0.w) + ww.y * b2f(v1.w) + ww.z * b2f(v2.w);
  ushort4 o = make_ushort4(f2b(r0), f2b(r1), f2b(r2), f2b(r3));
  *(ushort4*)&xcat[(size_t)bn * 512 + 256 + d0] = o;
}

// ---------------- bf16 MFMA GEMM: C[M][256] = A[M][K] * Bt[256][K]^T ----------------
template <int K>
__global__ __launch_bounds__(512) void gemm_bt(
    const unsigned short* __restrict__ A, const unsigned short* __restrict__ Bt,
    unsigned short* __restrict__ C) {
  __shared__ unsigned short Alds[128 * 32];
  __shared__ unsigned short Blds[256 * 32];
  int t = threadIdx.x;
  int lane = t & 63, wid = t >> 6;
  int wr = wid >> 2, wc = wid & 3;
  size_t bm = (size_t)blockIdx.x * 128;

  f32x4 acc[4][4] = {};

  int akc = (t & 3) * 8;
  const unsigned short* aSrc = A + (bm + (t >> 2)) * K + akc;
  const unsigned short* bSrc1 = Bt + (size_t)(t >> 2) * K + akc;
  const unsigned short* bSrc2 = Bt + (size_t)((t >> 2) + 128) * K + akc;
  char* aDst = (char*)Alds + wid * 1024;
  char* bDst1 = (char*)Blds + wid * 1024;
  char* bDst2 = (char*)Blds + 8192 + wid * 1024;

  for (int kt = 0; kt < K / 32; ++kt) {
    int ko = kt * 32;
    gload_lds16(aSrc + ko, aDst);
    gload_lds16(bSrc1 + ko, bDst1);
    gload_lds16(bSrc2 + ko, bDst2);
    __syncthreads();
    bf16x8 a[4], bfr[4];
#pragma unroll
    for (int m = 0; m < 4; ++m) {
      int row = wr * 64 + m * 16 + (lane & 15);
      a[m] = *(const bf16x8*)&Alds[row * 32 + (lane >> 4) * 8];
    }
#pragma unroll
    for (int n = 0; n < 4; ++n) {
      int col = wc * 64 + n * 16 + (lane & 15);
      bfr[n] = *(const bf16x8*)&Blds[col * 32 + (lane >> 4) * 8];
    }
#pragma unroll
    for (int m = 0; m < 4; ++m)
#pragma unroll
      for (int n = 0; n < 4; ++n)
        acc[m][n] = __builtin_amdgcn_mfma_f32_16x16x32_bf16(a[m], bfr[n], acc[m][n], 0, 0, 0);
    __syncthreads();
  }

  int crow0 = wr * 64 + (lane >> 4) * 4;
  int ccol0 = wc * 64 + (lane & 15);
#pragma unroll
  for (int m = 0; m < 4; ++m)
#pragma unroll
    for (int n = 0; n < 4; ++n)
#pragma unroll
      for (int j = 0; j < 4; ++j) {
        size_t r = bm + crow0 + m * 16 + j;
        C[r * 256 + ccol0 + n * 16] = f2b(acc[m][n][j]);
      }
}

// ---------------- BN stats: partial sums per 256-row block ----------------
__global__ __launch_bounds__(256) void stats_partial(
    const unsigned short* __restrict__ Y, float* __restrict__ ps, float* __restrict__ pq) {
  int blk = blockIdx.x;
  int c = threadIdx.x;
  const unsigned short* row = Y + (size_t)blk * 256 * 256 + c;
  float s = 0.f, q = 0.f;
#pragma unroll 4
  for (int r = 0; r < 256; ++r) {
    float v = b2f(row[(size_t)r * 256]);
    s += v; q += v * v;
  }
  ps[blk * 256 + c] = s;
  pq[blk * 256 + c] = q;
}

__global__ __launch_bounds__(256) void stats_final(
    const float* __restrict__ ps, const float* __restrict__ pq,
    const float* __restrict__ g, const float* __restrict__ be,
    float* __restrict__ scale, float* __restrict__ shift) {
  int c = threadIdx.x;
  float s = 0.f, q = 0.f;
  for (int r = 0; r < 256; ++r) { s += ps[r * 256 + c]; q += pq[r * 256 + c]; }
  float mean = s * (1.0f / 65536.0f);
  float var = fmaxf(q * (1.0f / 65536.0f) - mean * mean, 0.f);
  float sc = g[c] * rsqrtf(var + 1e-5f);
  scale[c] = sc;
  shift[c] = be[c] - mean * sc;
}

// ---------------- BN apply + ReLU (elementwise, 8 bf16/thread) ----------------
__global__ __launch_bounds__(256) void bnrelu_kernel(
    const unsigned short* __restrict__ Y, const float* __restrict__ scale,
    const float* __restrict__ shift, unsigned short* __restrict__ X) {
  size_t i = ((size_t)blockIdx.x * 256 + threadIdx.x) * 8;
  int c = (int)(i & 255);
  ushort4 v0 = *(const ushort4*)&Y[i];
  ushort4 v1 = *(const ushort4*)&Y[i + 4];
  float4 s0 = *(const float4*)&scale[c];
  float4 s1 = *(const float4*)&scale[c + 4];
  float4 h0 = *(const float4*)&shift[c];
  float4 h1 = *(const float4*)&shift[c + 4];
  ushort4 o0, o1;
  o0.x = f2b(fmaxf(b2f(v0.x) * s0.x + h0.x, 0.f));
  o0.y = f2b(fmaxf(b2f(v0.y) * s0.y + h0.y, 0.f));
  o0.z = f2b(fmaxf(b2f(v0.z) * s0.z + h0.z, 0.f));
  o0.w = f2b(fmaxf(b2f(v0.w) * s0.w + h0.w, 0.f));
  o1.x = f2b(fmaxf(b2f(v1.x) * s1.x + h1.x, 0.f));
  o1.y = f2b(fmaxf(b2f(v1.y) * s1.y + h1.y, 0.f));
  o1.z = f2b(fmaxf(b2f(v1.z) * s1.z + h1.z, 0.f));
  o1.w = f2b(fmaxf(b2f(v1.w) * s1.w + h1.w, 0.f));
  *(ushort4*)&X[i] = o0;
  *(ushort4*)&X[i + 4] = o1;
}

// ------- final: BN+ReLU + transpose [bn][o] -> out f32 [B][256][N] -------
__global__ __launch_bounds__(256) void final_kernel(
    const unsigned short* __restrict__ Y1, const float* __restrict__ scale,
    const float* __restrict__ shift, float* __restrict__ out) {
  __shared__ float lds[32][65];
  int n0 = blockIdx.x * 32, o0 = blockIdx.y * 64, b = blockIdx.z;
  int t = threadIdx.x;
  int tx = t & 63, ty = t >> 6;  // ty 0..3
#pragma unroll
  for (int rr = 0; rr < 8; ++rr) {
    int nl = ty + rr * 4;
    lds[nl][tx] = b2f(Y1[((size_t)b * N_ + n0 + nl) * 256 + o0 + tx]);
  }
  __syncthreads();
  int wn = t & 31, wo = t >> 5;  // wo 0..7
#pragma unroll
  for (int it = 0; it < 8; ++it) {
    int ol = wo + it * 8;
    int o = o0 + ol;
    float v = fmaxf(lds[wn][ol] * scale[o] + shift[o], 0.f);
    out[((size_t)b * 256 + o) * N_ + n0 + wn] = v;
  }
}

// ---------------- workspace layout (bytes) ----------------
static const size_t OFF_XCAT = 0;                       // 67108864 (Y1 aliases)
static const size_t OFF_P2T  = 67108864;                // 8388608
static const size_t OFF_KI   = OFF_P2T + 8388608;       // 1048576
static const size_t OFF_KW   = OFF_KI + 1048576;        // 1048576
static const size_t OFF_Y0   = OFF_KW + 1048576;        // 33554432
static const size_t OFF_X1   = OFF_Y0 + 33554432;       // 33554432
static const size_t OFF_W0B  = OFF_X1 + 33554432;       // 262144
static const size_t OFF_W1B  = OFF_W0B + 262144;        // 131072
static const size_t OFF_PS   = OFF_W1B + 131072;        // 262144
static const size_t OFF_PQ   = OFF_PS + 262144;         // 262144
static const size_t OFF_SC0  = OFF_PQ + 262144;         // 1024
static const size_t OFF_SH0  = OFF_SC0 + 1024;
static const size_t OFF_SC1  = OFF_SH0 + 1024;
static const size_t OFF_SH1  = OFF_SC1 + 1024;

extern "C" void kernel_launch(void* const* d_in, const int* in_sizes, int n_in,
                              void* d_out, int out_size, void* d_ws, size_t ws_size,
                              hipStream_t stream) {
  const float* xyz1    = (const float*)d_in[0];
  const float* xyz2    = (const float*)d_in[1];
  const float* points1 = (const float*)d_in[2];
  const float* points2 = (const float*)d_in[3];
  const float* W0      = (const float*)d_in[4];
  // d_in[5] = b0 (cancels exactly inside BatchNorm; skipped)
  const float* W1      = (const float*)d_in[6];
  // d_in[7] = b1 (cancels)
  const float* g0      = (const float*)d_in[8];
  const float* be0     = (const float*)d_in[9];
  const float* g1      = (const float*)d_in[10];
  const float* be1     = (const float*)d_in[11];

  char* ws = (char*)d_ws;
  unsigned short* xcat = (unsigned short*)(ws + OFF_XCAT);
  unsigned short* p2t  = (unsigned short*)(ws + OFF_P2T);
  int4*  ki  = (int4*)(ws + OFF_KI);
  float4* kw = (float4*)(ws + OFF_KW);
  unsigned short* y0  = (unsigned short*)(ws + OFF_Y0);
  unsigned short* x1  = (unsigned short*)(ws + OFF_X1);
  unsigned short* y1  = (unsigned short*)(ws + OFF_XCAT);  // alias: xcat dead after GEMM0
  unsigned short* w0b = (unsigned short*)(ws + OFF_W0B);
  unsigned short* w1b = (unsigned short*)(ws + OFF_W1B);
  float* ps  = (float*)(ws + OFF_PS);
  float* pq  = (float*)(ws + OFF_PQ);
  float* sc0 = (float*)(ws + OFF_SC0);
  float* sh0 = (float*)(ws + OFF_SH0);
  float* sc1 = (float*)(ws + OFF_SC1);
  float* sh1 = (float*)(ws + OFF_SH1);

  dim3 blk(256);

  cast_f32_bf16<<<dim3(512), blk, 0, stream>>>(W0, w0b, 256 * 512);
  cast_f32_bf16<<<dim3(256), blk, 0, stream>>>(W1, w1b, 256 * 256);

  transpose_cast<<<dim3(N_ / 32, 4, B_), blk, 0, stream>>>(points1, xcat, N_, 512);
  transpose_cast<<<dim3(S_ / 32, 4, B_), blk, 0, stream>>>(points2, p2t, S_, 256);

  knn_kernel<<<dim3(N_ / 256, B_), blk, 0, stream>>>(xyz1, xyz2, ki, kw);
  interp_kernel<<<dim3(BN_TOT / 4), blk, 0, stream>>>(p2t, ki, kw, xcat);

  gemm_bt<512><<<dim3(BN_TOT / 128), dim3(512), 0, stream>>>(xcat, w0b, y0);

  stats_partial<<<dim3(256), blk, 0, stream>>>(y0, ps, pq);
  stats_final<<<dim3(1), blk, 0, stream>>>(ps, pq, g0, be0, sc0, sh0);
  bnrelu_kernel<<<dim3(BN_TOT * 256 / 8 / 256), blk, 0, stream>>>(y0, sc0, sh0, x1);

  gemm_bt<256><<<dim3(BN_TOT / 128), dim3(512), 0, stream>>>(x1, w1b, y1);

  stats_partial<<<dim3(256), blk, 0, stream>>>(y1, ps, pq);
  stats_final<<<dim3(1), blk, 0, stream>>>(ps, pq, g1, be1, sc1, sh1);

  final_kernel<<<dim3(N_ / 32, 4, B_), blk, 0, stream>>>(y1, sc1, sh1, (float*)d_out);
}

// Round 2
// 311.786 us; speedup vs baseline: 1.1041x; 1.1041x over previous
//
#include <hip/hip_runtime.h>
#include <stdint.h>

#define B_ 8
#define N_ 8192
#define S_ 2048
#define D_ 256
#define BN_TOT (B_ * N_)   // 65536
#define SPLIT_ 4
#define SCH_ (S_ / SPLIT_) // 512

typedef __attribute__((ext_vector_type(8))) short bf16x8;
typedef __attribute__((ext_vector_type(4))) float f32x4;

__device__ __forceinline__ float b2f(unsigned short u) {
  union { float f; uint32_t i; } v; v.i = ((uint32_t)u) << 16; return v.f;
}
__device__ __forceinline__ unsigned short f2b(float f) {
  union { float f; uint32_t i; } v; v.f = f;
  uint32_t r = v.i + 0x7FFF + ((v.i >> 16) & 1);
  return (unsigned short)(r >> 16);
}

__device__ __forceinline__ void gload_lds16(const void* g, void* l) {
  __builtin_amdgcn_global_load_lds(
      (const __attribute__((address_space(1))) void*)g,
      (__attribute__((address_space(3))) void*)l, 16, 0, 0);
}

// ---------------- simple f32 -> bf16 cast (weights) ----------------
__global__ __launch_bounds__(256) void cast_f32_bf16(
    const float* __restrict__ in, unsigned short* __restrict__ out, int n) {
  int i = blockIdx.x * 256 + threadIdx.x;
  if (i < n) out[i] = f2b(in[i]);
}

// ------- transpose-cast: f32 [B][256][L] -> bf16 [B][L][ldo] (col 0..255) -------
__global__ __launch_bounds__(256) void transpose_cast(
    const float* __restrict__ in, unsigned short* __restrict__ out,
    int L, int ldo) {
  __shared__ float lds[64][33];
  int c0 = blockIdx.x * 32;
  int r0 = blockIdx.y * 64;
  int b = blockIdx.z;
  int t = threadIdx.x;
  int tx = t & 31, ty = t >> 5;  // ty 0..7
  const float* src = in + ((size_t)b * 256 + r0) * L + c0;
#pragma unroll
  for (int rr = 0; rr < 8; ++rr) {
    int r = ty + rr * 8;
    lds[r][tx] = src[(size_t)r * L + tx];
  }
  __syncthreads();
  int wr = t & 31;   // r-pair
  int wc = t >> 5;   // 0..7
#pragma unroll
  for (int it = 0; it < 4; ++it) {
    int cl = wc + it * 8;
    unsigned short a = f2b(lds[wr * 2][cl]);
    unsigned short b2 = f2b(lds[wr * 2 + 1][cl]);
    uint32_t packed = (uint32_t)a | ((uint32_t)b2 << 16);
    *(uint32_t*)&out[((size_t)b * L + (c0 + cl)) * ldo + r0 + wr * 2] = packed;
  }
}

// ---------------- pack candidates: xyz2 [B][3][S] -> float4 (x,y,z,n2f) ----------------
__global__ __launch_bounds__(256) void pack_cand(
    const float* __restrict__ xyz2, float4* __restrict__ cand) {
  int i = blockIdx.x * 256 + threadIdx.x;  // over B_*S_
  int b = i >> 11, s = i & (S_ - 1);
  const float* x2 = xyz2 + (size_t)b * 3 * S_;
  float x = x2[s], y = x2[S_ + s], z = x2[2 * S_ + s];
  double n2 = (double)x * x + (double)y * y + (double)z * z;
  cand[i] = make_float4(x, y, z, (float)n2);
}

// ---------------- 3-NN split pass: fp32 screen + fp64 confirm ----------------
// Screen: candidate can enter top-3 only if d64 < d2_running. |d32-d64| <= ~1e-4
// (coords <= ~6 sigma => intermediates <= ~200, ~6 fp32 ops). Margin 1e-3 >> err.
__global__ __launch_bounds__(256) void knn_split(
    const float* __restrict__ xyz1, const float4* __restrict__ cand,
    double4* __restrict__ Dp, int4* __restrict__ Ip) {
  int b = blockIdx.y;
  int split = blockIdx.z;
  int n = blockIdx.x * 256 + threadIdx.x;
  const float* x1 = xyz1 + (size_t)b * 3 * N_;
  float pxf = x1[n], pyf = x1[N_ + n], pzf = x1[2 * N_ + n];
  double px = pxf, py = pyf, pz = pzf;
  double n1 = px * px + py * py + pz * pz;
  float n1f = (float)n1;
  const float4* cb = cand + b * S_ + split * SCH_;
  double d0 = 1e300, d1 = 1e300, d2 = 1e300;
  int i0 = 0, i1 = 0, i2 = 0;
  float t = 3.4e38f;
#pragma unroll 4
  for (int s = 0; s < SCH_; ++s) {
    float4 c = cb[s];  // wave-uniform address -> scalar load
    float dot = pxf * c.x + pyf * c.y + pzf * c.z;
    float d32 = (n1f + c.w) - 2.0f * dot;
    if (d32 < t) {
      double cx = c.x, cy = c.y, cz = c.z;
      double dot64 = px * cx + py * cy + pz * cz;
      double n2 = cx * cx + cy * cy + cz * cz;
      double dd = (n1 + n2) - 2.0 * dot64;
      int gs = split * SCH_ + s;
      bool c0 = dd < d0, c1 = dd < d1, c2 = dd < d2;
      i2 = c1 ? i1 : (c2 ? gs : i2);
      d2 = c1 ? d1 : (c2 ? dd : d2);
      i1 = c0 ? i0 : (c1 ? gs : i1);
      d1 = c0 ? d0 : (c1 ? dd : d1);
      i0 = c0 ? gs : i0;
      d0 = c0 ? dd : d0;
      t = (float)d2 + 1e-3f;
    }
  }
  int q = b * N_ + n;
  Dp[(size_t)split * BN_TOT + q] = make_double4(d0, d1, d2, 0.0);
  Ip[(size_t)split * BN_TOT + q] = make_int4(i0, i1, i2, 0);
}

// ---------------- merge split partials (exact fp64, tie-stable) ----------------
__global__ __launch_bounds__(256) void knn_merge(
    const double4* __restrict__ Dp, const int4* __restrict__ Ip,
    int4* __restrict__ knn_i, float4* __restrict__ knn_w) {
  int q = blockIdx.x * 256 + threadIdx.x;
  double d0 = 1e300, d1 = 1e300, d2 = 1e300;
  int i0 = 0, i1 = 0, i2 = 0;
#define INS_(dd, gs)                          \
  {                                           \
    bool c0 = dd < d0, c1 = dd < d1, c2 = dd < d2; \
    i2 = c1 ? i1 : (c2 ? gs : i2);            \
    d2 = c1 ? d1 : (c2 ? dd : d2);            \
    i1 = c0 ? i0 : (c1 ? gs : i1);            \
    d1 = c0 ? d0 : (c1 ? dd : d1);            \
    i0 = c0 ? gs : i0;                        \
    d0 = c0 ? dd : d0;                        \
  }
#pragma unroll
  for (int sp = 0; sp < SPLIT_; ++sp) {
    double4 D = Dp[(size_t)sp * BN_TOT + q];
    int4 I = Ip[(size_t)sp * BN_TOT + q];
    INS_(D.x, I.x);
    INS_(D.y, I.y);
    INS_(D.z, I.z);
  }
#undef INS_
  float f0 = (float)d0, f1 = (float)d1, f2 = (float)d2;
  float w0 = 1.0f / (f0 + 1e-8f), w1 = 1.0f / (f1 + 1e-8f), w2 = 1.0f / (f2 + 1e-8f);
  float inv = 1.0f / (w0 + w1 + w2);
  knn_i[q] = make_int4(i0, i1, i2, 0);
  knn_w[q] = make_float4(w0 * inv, w1 * inv, w2 * inv, 0.f);
}

// ---------------- gather-interpolate -> Xcat[:,256:512] ----------------
__global__ __launch_bounds__(256) void interp_kernel(
    const unsigned short* __restrict__ p2t, const int4* __restrict__ knn_i,
    const float4* __restrict__ knn_w, unsigned short* __restrict__ xcat) {
  int wid = threadIdx.x >> 6, lane = threadIdx.x & 63;
  int bn = blockIdx.x * 4 + wid;
  int b = bn >> 13;
  int4 ii = knn_i[bn];
  float4 ww = knn_w[bn];
  int d0 = lane * 4;
  const unsigned short* base = p2t + (size_t)b * S_ * 256;
  ushort4 v0 = *(const ushort4*)(base + (size_t)ii.x * 256 + d0);
  ushort4 v1 = *(const ushort4*)(base + (size_t)ii.y * 256 + d0);
  ushort4 v2 = *(const ushort4*)(base + (size_t)ii.z * 256 + d0);
  float r0 = ww.x * b2f(v0.x) + ww.y * b2f(v1.x) + ww.z * b2f(v2.x);
  float r1 = ww.x * b2f(v0.y) + ww.y * b2f(v1.y) + ww.z * b2f(v2.y);
  float r2 = ww.x * b2f(v0.z) + ww.y * b2f(v1.z) + ww.z * b2f(v2.z);
  float r3 = ww.x * b2f(v0.w) + ww.y * b2f(v1.w) + ww.z * b2f(v2.w);
  ushort4 o = make_ushort4(f2b(r0), f2b(r1), f2b(r2), f2b(r3));
  *(ushort4*)&xcat[(size_t)bn * 512 + 256 + d0] = o;
}

// ---------------- bf16 MFMA GEMM: C[M][256] = A[M][K] * Bt[256][K]^T ----------------
template <int K>
__global__ __launch_bounds__(512) void gemm_bt(
    const unsigned short* __restrict__ A, const unsigned short* __restrict__ Bt,
    unsigned short* __restrict__ C) {
  __shared__ unsigned short Alds[128 * 32];
  __shared__ unsigned short Blds[256 * 32];
  int t = threadIdx.x;
  int lane = t & 63, wid = t >> 6;
  int wr = wid >> 2, wc = wid & 3;
  size_t bm = (size_t)blockIdx.x * 128;

  f32x4 acc[4][4] = {};

  int akc = (t & 3) * 8;
  const unsigned short* aSrc = A + (bm + (t >> 2)) * K + akc;
  const unsigned short* bSrc1 = Bt + (size_t)(t >> 2) * K + akc;
  const unsigned short* bSrc2 = Bt + (size_t)((t >> 2) + 128) * K + akc;
  char* aDst = (char*)Alds + wid * 1024;
  char* bDst1 = (char*)Blds + wid * 1024;
  char* bDst2 = (char*)Blds + 8192 + wid * 1024;

  for (int kt = 0; kt < K / 32; ++kt) {
    int ko = kt * 32;
    gload_lds16(aSrc + ko, aDst);
    gload_lds16(bSrc1 + ko, bDst1);
    gload_lds16(bSrc2 + ko, bDst2);
    __syncthreads();
    bf16x8 a[4], bfr[4];
#pragma unroll
    for (int m = 0; m < 4; ++m) {
      int row = wr * 64 + m * 16 + (lane & 15);
      a[m] = *(const bf16x8*)&Alds[row * 32 + (lane >> 4) * 8];
    }
#pragma unroll
    for (int n = 0; n < 4; ++n) {
      int col = wc * 64 + n * 16 + (lane & 15);
      bfr[n] = *(const bf16x8*)&Blds[col * 32 + (lane >> 4) * 8];
    }
#pragma unroll
    for (int m = 0; m < 4; ++m)
#pragma unroll
      for (int n = 0; n < 4; ++n)
        acc[m][n] = __builtin_amdgcn_mfma_f32_16x16x32_bf16(a[m], bfr[n], acc[m][n], 0, 0, 0);
    __syncthreads();
  }

  int crow0 = wr * 64 + (lane >> 4) * 4;
  int ccol0 = wc * 64 + (lane & 15);
#pragma unroll
  for (int m = 0; m < 4; ++m)
#pragma unroll
    for (int n = 0; n < 4; ++n)
#pragma unroll
      for (int j = 0; j < 4; ++j) {
        size_t r = bm + crow0 + m * 16 + j;
        C[r * 256 + ccol0 + n * 16] = f2b(acc[m][n][j]);
      }
}

// ---------------- BN stats: partial sums per 256-row block ----------------
__global__ __launch_bounds__(256) void stats_partial(
    const unsigned short* __restrict__ Y, float* __restrict__ ps, float* __restrict__ pq) {
  int blk = blockIdx.x;
  int c = threadIdx.x;
  const unsigned short* row = Y + (size_t)blk * 256 * 256 + c;
  float s = 0.f, q = 0.f;
#pragma unroll 4
  for (int r = 0; r < 256; ++r) {
    float v = b2f(row[(size_t)r * 256]);
    s += v; q += v * v;
  }
  ps[blk * 256 + c] = s;
  pq[blk * 256 + c] = q;
}

__global__ __launch_bounds__(256) void stats_final(
    const float* __restrict__ ps, const float* __restrict__ pq,
    const float* __restrict__ g, const float* __restrict__ be,
    float* __restrict__ scale, float* __restrict__ shift) {
  int c = threadIdx.x;
  float s = 0.f, q = 0.f;
  for (int r = 0; r < 256; ++r) { s += ps[r * 256 + c]; q += pq[r * 256 + c]; }
  float mean = s * (1.0f / 65536.0f);
  float var = fmaxf(q * (1.0f / 65536.0f) - mean * mean, 0.f);
  float sc = g[c] * rsqrtf(var + 1e-5f);
  scale[c] = sc;
  shift[c] = be[c] - mean * sc;
}

// ---------------- BN apply + ReLU (elementwise, 8 bf16/thread) ----------------
__global__ __launch_bounds__(256) void bnrelu_kernel(
    const unsigned short* __restrict__ Y, const float* __restrict__ scale,
    const float* __restrict__ shift, unsigned short* __restrict__ X) {
  size_t i = ((size_t)blockIdx.x * 256 + threadIdx.x) * 8;
  int c = (int)(i & 255);
  ushort4 v0 = *(const ushort4*)&Y[i];
  ushort4 v1 = *(const ushort4*)&Y[i + 4];
  float4 s0 = *(const float4*)&scale[c];
  float4 s1 = *(const float4*)&scale[c + 4];
  float4 h0 = *(const float4*)&shift[c];
  float4 h1 = *(const float4*)&shift[c + 4];
  ushort4 o0, o1;
  o0.x = f2b(fmaxf(b2f(v0.x) * s0.x + h0.x, 0.f));
  o0.y = f2b(fmaxf(b2f(v0.y) * s0.y + h0.y, 0.f));
  o0.z = f2b(fmaxf(b2f(v0.z) * s0.z + h0.z, 0.f));
  o0.w = f2b(fmaxf(b2f(v0.w) * s0.w + h0.w, 0.f));
  o1.x = f2b(fmaxf(b2f(v1.x) * s1.x + h1.x, 0.f));
  o1.y = f2b(fmaxf(b2f(v1.y) * s1.y + h1.y, 0.f));
  o1.z = f2b(fmaxf(b2f(v1.z) * s1.z + h1.z, 0.f));
  o1.w = f2b(fmaxf(b2f(v1.w) * s1.w + h1.w, 0.f));
  *(ushort4*)&X[i] = o0;
  *(ushort4*)&X[i + 4] = o1;
}

// ------- final: BN+ReLU + transpose [bn][o] -> out f32 [B][256][N] -------
__global__ __launch_bounds__(256) void final_kernel(
    const unsigned short* __restrict__ Y1, const float* __restrict__ scale,
    const float* __restrict__ shift, float* __restrict__ out) {
  __shared__ float lds[32][65];
  int n0 = blockIdx.x * 32, o0 = blockIdx.y * 64, b = blockIdx.z;
  int t = threadIdx.x;
  int tx = t & 63, ty = t >> 6;  // ty 0..3
#pragma unroll
  for (int rr = 0; rr < 8; ++rr) {
    int nl = ty + rr * 4;
    lds[nl][tx] = b2f(Y1[((size_t)b * N_ + n0 + nl) * 256 + o0 + tx]);
  }
  __syncthreads();
  int wn = t & 31, wo = t >> 5;  // wo 0..7
#pragma unroll
  for (int it = 0; it < 8; ++it) {
    int ol = wo + it * 8;
    int o = o0 + ol;
    float v = fmaxf(lds[wn][ol] * scale[o] + shift[o], 0.f);
    out[((size_t)b * 256 + o) * N_ + n0 + wn] = v;
  }
}

// ---------------- workspace layout (bytes) ----------------
static const size_t OFF_XCAT = 0;                       // 67108864 (y1 aliases)
static const size_t OFF_P2T  = 67108864;                // 8388608
static const size_t OFF_KI   = OFF_P2T + 8388608;       // 1048576
static const size_t OFF_KW   = OFF_KI + 1048576;        // 1048576
static const size_t OFF_Y0   = OFF_KW + 1048576;        // 33554432 (Dp/Ip alias)
static const size_t OFF_X1   = OFF_Y0 + 33554432;       // 33554432 (cand aliases)
static const size_t OFF_W0B  = OFF_X1 + 33554432;       // 262144
static const size_t OFF_W1B  = OFF_W0B + 262144;        // 131072
static const size_t OFF_PS   = OFF_W1B + 131072;        // 262144
static const size_t OFF_PQ   = OFF_PS + 262144;         // 262144
static const size_t OFF_SC0  = OFF_PQ + 262144;         // 1024
static const size_t OFF_SH0  = OFF_SC0 + 1024;
static const size_t OFF_SC1  = OFF_SH0 + 1024;
static const size_t OFF_SH1  = OFF_SC1 + 1024;

extern "C" void kernel_launch(void* const* d_in, const int* in_sizes, int n_in,
                              void* d_out, int out_size, void* d_ws, size_t ws_size,
                              hipStream_t stream) {
  const float* xyz1    = (const float*)d_in[0];
  const float* xyz2    = (const float*)d_in[1];
  const float* points1 = (const float*)d_in[2];
  const float* points2 = (const float*)d_in[3];
  const float* W0      = (const float*)d_in[4];
  // d_in[5] = b0 (cancels exactly inside BatchNorm; skipped)
  const float* W1      = (const float*)d_in[6];
  // d_in[7] = b1 (cancels)
  const float* g0      = (const float*)d_in[8];
  const float* be0     = (const float*)d_in[9];
  const float* g1      = (const float*)d_in[10];
  const float* be1     = (const float*)d_in[11];

  char* ws = (char*)d_ws;
  unsigned short* xcat = (unsigned short*)(ws + OFF_XCAT);
  unsigned short* p2t  = (unsigned short*)(ws + OFF_P2T);
  int4*  ki  = (int4*)(ws + OFF_KI);
  float4* kw = (float4*)(ws + OFF_KW);
  unsigned short* y0  = (unsigned short*)(ws + OFF_Y0);
  unsigned short* x1  = (unsigned short*)(ws + OFF_X1);
  unsigned short* y1  = (unsigned short*)(ws + OFF_XCAT);  // alias: xcat dead after GEMM0
  unsigned short* w0b = (unsigned short*)(ws + OFF_W0B);
  unsigned short* w1b = (unsigned short*)(ws + OFF_W1B);
  float* ps  = (float*)(ws + OFF_PS);
  float* pq  = (float*)(ws + OFF_PQ);
  float* sc0 = (float*)(ws + OFF_SC0);
  float* sh0 = (float*)(ws + OFF_SH0);
  float* sc1 = (float*)(ws + OFF_SC1);
  float* sh1 = (float*)(ws + OFF_SH1);
  // aliases (regions dead at time of use):
  float4*  cand = (float4*)(ws + OFF_X1);                 // dead before bnrelu writes x1
  double4* Dp   = (double4*)(ws + OFF_Y0);                // dead before gemm0 writes y0
  int4*    Ip   = (int4*)(ws + OFF_Y0 + (size_t)SPLIT_ * BN_TOT * 32);

  dim3 blk(256);

  cast_f32_bf16<<<dim3(512), blk, 0, stream>>>(W0, w0b, 256 * 512);
  cast_f32_bf16<<<dim3(256), blk, 0, stream>>>(W1, w1b, 256 * 256);

  pack_cand<<<dim3(B_ * S_ / 256), blk, 0, stream>>>(xyz2, cand);
  knn_split<<<dim3(N_ / 256, B_, SPLIT_), blk, 0, stream>>>(xyz1, cand, Dp, Ip);
  knn_merge<<<dim3(BN_TOT / 256), blk, 0, stream>>>(Dp, Ip, ki, kw);

  transpose_cast<<<dim3(N_ / 32, 4, B_), blk, 0, stream>>>(points1, xcat, N_, 512);
  transpose_cast<<<dim3(S_ / 32, 4, B_), blk, 0, stream>>>(points2, p2t, S_, 256);

  interp_kernel<<<dim3(BN_TOT / 4), blk, 0, stream>>>(p2t, ki, kw, xcat);

  gemm_bt<512><<<dim3(BN_TOT / 128), dim3(512), 0, stream>>>(xcat, w0b, y0);

  stats_partial<<<dim3(256), blk, 0, stream>>>(y0, ps, pq);
  stats_final<<<dim3(1), blk, 0, stream>>>(ps, pq, g0, be0, sc0, sh0);
  bnrelu_kernel<<<dim3(BN_TOT * 256 / 8 / 256), blk, 0, stream>>>(y0, sc0, sh0, x1);

  gemm_bt<256><<<dim3(BN_TOT / 128), dim3(512), 0, stream>>>(x1, w1b, y1);

  stats_partial<<<dim3(256), blk, 0, stream>>>(y1, ps, pq);
  stats_final<<<dim3(1), blk, 0, stream>>>(ps, pq, g1, be1, sc1, sh1);

  final_kernel<<<dim3(N_ / 32, 4, B_), blk, 0, stream>>>(y1, sc1, sh1, (float*)d_out);
}

// Round 3
// 256.474 us; speedup vs baseline: 1.3422x; 1.2157x over previous
//
#include <hip/hip_runtime.h>
#include <stdint.h>

#define B_ 8
#define N_ 8192
#define S_ 2048
#define D_ 256
#define BN_TOT (B_ * N_)   // 65536
#define SPLIT_ 8
#define SCH_ (S_ / SPLIT_) // 256
#define MAXH_ 12

typedef __attribute__((ext_vector_type(8))) short bf16x8;
typedef __attribute__((ext_vector_type(4))) float f32x4;

__device__ __forceinline__ float b2f(unsigned short u) {
  union { float f; uint32_t i; } v; v.i = ((uint32_t)u) << 16; return v.f;
}
__device__ __forceinline__ unsigned short f2b(float f) {
  union { float f; uint32_t i; } v; v.f = f;
  uint32_t r = v.i + 0x7FFF + ((v.i >> 16) & 1);
  return (unsigned short)(r >> 16);
}

__device__ __forceinline__ void gload_lds16(const void* g, void* l) {
  __builtin_amdgcn_global_load_lds(
      (const __attribute__((address_space(1))) void*)g,
      (__attribute__((address_space(3))) void*)l, 16, 0, 0);
}

// ---------------- simple f32 -> bf16 cast (weights) ----------------
__global__ __launch_bounds__(256) void cast_f32_bf16(
    const float* __restrict__ in, unsigned short* __restrict__ out, int n) {
  int i = blockIdx.x * 256 + threadIdx.x;
  if (i < n) out[i] = f2b(in[i]);
}

// ------- transpose-cast: f32 [B][256][L] -> bf16 [B][L][ldo] (col 0..255) -------
__global__ __launch_bounds__(256) void transpose_cast(
    const float* __restrict__ in, unsigned short* __restrict__ out,
    int L, int ldo) {
  __shared__ float lds[64][33];
  int c0 = blockIdx.x * 32;
  int r0 = blockIdx.y * 64;
  int b = blockIdx.z;
  int t = threadIdx.x;
  int tx = t & 31, ty = t >> 5;  // ty 0..7
  const float* src = in + ((size_t)b * 256 + r0) * L + c0;
#pragma unroll
  for (int rr = 0; rr < 8; ++rr) {
    int r = ty + rr * 8;
    lds[r][tx] = src[(size_t)r * L + tx];
  }
  __syncthreads();
  int wr = t & 31;   // r-pair
  int wc = t >> 5;   // 0..7
#pragma unroll
  for (int it = 0; it < 4; ++it) {
    int cl = wc + it * 8;
    unsigned short a = f2b(lds[wr * 2][cl]);
    unsigned short b2 = f2b(lds[wr * 2 + 1][cl]);
    uint32_t packed = (uint32_t)a | ((uint32_t)b2 << 16);
    *(uint32_t*)&out[((size_t)b * L + (c0 + cl)) * ldo + r0 + wr * 2] = packed;
  }
}

// ---------------- pack candidates: xyz2 [B][3][S] -> float4 (x,y,z,n2/2) ----------------
__global__ __launch_bounds__(256) void pack_cand(
    const float* __restrict__ xyz2, float4* __restrict__ cand) {
  int i = blockIdx.x * 256 + threadIdx.x;  // over B_*S_
  int b = i >> 11, s = i & (S_ - 1);
  const float* x2 = xyz2 + (size_t)b * 3 * S_;
  float x = x2[s], y = x2[S_ + s], z = x2[2 * S_ + s];
  double n2 = (double)x * x + (double)y * y + (double)z * z;
  cand[i] = make_float4(x, y, z, (float)(0.5 * n2));
}

// ---------------- 3-NN split pass ----------------
// Pass 1: branchless fp32 top-3 VALUES (m = d/2 scale) via min/max network.
// Pass 2: record s with m < d2 + 6e-4 to per-lane LDS list (err bound ~5e-5).
// Phase 3: fp64-exact confirm+order of the ~3 recorded candidates per lane.
__global__ __launch_bounds__(256) void knn_split(
    const float* __restrict__ xyz1, const float4* __restrict__ cand,
    double4* __restrict__ Dp, int4* __restrict__ Ip) {
  __shared__ unsigned short hits[256 * MAXH_];
  int b = blockIdx.y;
  int split = blockIdx.z;
  int n = blockIdx.x * 256 + threadIdx.x;
  const float* x1 = xyz1 + (size_t)b * 3 * N_;
  float pxf = x1[n], pyf = x1[N_ + n], pzf = x1[2 * N_ + n];
  double px = pxf, py = pyf, pz = pzf;
  double n1 = px * px + py * py + pz * pz;
  float h = (float)(0.5 * n1);
  const float4* cb = cand + b * S_ + split * SCH_;

  // ---- pass 1: branchless fp32 top-3 values ----
  float d0 = 3.4e38f, d1 = 3.4e38f, d2 = 3.4e38f;
#pragma unroll 8
  for (int s = 0; s < SCH_; ++s) {
    float4 c = cb[s];  // wave-uniform -> scalar load
    float m = fmaf(-pzf, c.z, fmaf(-pyf, c.y, fmaf(-pxf, c.x, h + c.w)));
    float t1 = fmaxf(d0, m);
    d0 = fminf(d0, m);
    float t2 = fmaxf(d1, t1);
    d1 = fminf(d1, t1);
    d2 = fminf(d2, t2);
  }

  // ---- pass 2: record candidates below threshold ----
  float thr = d2 + 6e-4f;
  int cnt = 0;
  unsigned short* myh = hits + threadIdx.x * MAXH_;
#pragma unroll 4
  for (int s = 0; s < SCH_; ++s) {
    float4 c = cb[s];
    float m = fmaf(-pzf, c.z, fmaf(-pyf, c.y, fmaf(-pxf, c.x, h + c.w)));
    if (m < thr) {
      if (cnt < MAXH_) myh[cnt] = (unsigned short)s;
      cnt++;
    }
  }

  // ---- phase 3: fp64 confirm (exact ordering, tie-stable: ascending s, strict <) ----
  double e0 = 1e300, e1 = 1e300, e2 = 1e300;
  int i0 = 0, i1 = 0, i2 = 0;
#define INS_(dd, gs)                               \
  {                                                \
    bool c0 = dd < e0, c1 = dd < e1, c2 = dd < e2; \
    i2 = c1 ? i1 : (c2 ? gs : i2);                 \
    e2 = c1 ? e1 : (c2 ? dd : e2);                 \
    i1 = c0 ? i0 : (c1 ? gs : i1);                 \
    e1 = c0 ? e0 : (c1 ? dd : e1);                 \
    i0 = c0 ? gs : i0;                             \
    e0 = c0 ? dd : e0;                             \
  }
  if (cnt <= MAXH_) {
    for (int j = 0; j < cnt; ++j) {
      int s = myh[j];
      float4 c = cb[s];
      double cx = c.x, cy = c.y, cz = c.z;
      double dot64 = px * cx + py * cy + pz * cz;
      double n2 = cx * cx + cy * cy + cz * cz;
      double dd = (n1 + n2) - 2.0 * dot64;
      int gs = split * SCH_ + s;
      INS_(dd, gs);
    }
  } else {
    // overflow fallback (probability ~0): full fp64 scan of the chunk
    for (int s = 0; s < SCH_; ++s) {
      float4 c = cb[s];
      double cx = c.x, cy = c.y, cz = c.z;
      double dot64 = px * cx + py * cy + pz * cz;
      double n2 = cx * cx + cy * cy + cz * cz;
      double dd = (n1 + n2) - 2.0 * dot64;
      int gs = split * SCH_ + s;
      INS_(dd, gs);
    }
  }
#undef INS_
  int q = b * N_ + n;
  Dp[(size_t)split * BN_TOT + q] = make_double4(e0, e1, e2, 0.0);
  Ip[(size_t)split * BN_TOT + q] = make_int4(i0, i1, i2, 0);
}

// ---------------- merge split partials (exact fp64, tie-stable) ----------------
__global__ __launch_bounds__(256) void knn_merge(
    const double4* __restrict__ Dp, const int4* __restrict__ Ip,
    int4* __restrict__ knn_i, float4* __restrict__ knn_w) {
  int q = blockIdx.x * 256 + threadIdx.x;
  double d0 = 1e300, d1 = 1e300, d2 = 1e300;
  int i0 = 0, i1 = 0, i2 = 0;
#define INS_(dd, gs)                          \
  {                                           \
    bool c0 = dd < d0, c1 = dd < d1, c2 = dd < d2; \
    i2 = c1 ? i1 : (c2 ? gs : i2);            \
    d2 = c1 ? d1 : (c2 ? dd : d2);            \
    i1 = c0 ? i0 : (c1 ? gs : i1);            \
    d1 = c0 ? d0 : (c1 ? dd : d1);            \
    i0 = c0 ? gs : i0;                        \
    d0 = c0 ? dd : d0;                        \
  }
#pragma unroll
  for (int sp = 0; sp < SPLIT_; ++sp) {
    double4 D = Dp[(size_t)sp * BN_TOT + q];
    int4 I = Ip[(size_t)sp * BN_TOT + q];
    INS_(D.x, I.x);
    INS_(D.y, I.y);
    INS_(D.z, I.z);
  }
#undef INS_
  float f0 = (float)d0, f1 = (float)d1, f2 = (float)d2;
  float w0 = 1.0f / (f0 + 1e-8f), w1 = 1.0f / (f1 + 1e-8f), w2 = 1.0f / (f2 + 1e-8f);
  float inv = 1.0f / (w0 + w1 + w2);
  knn_i[q] = make_int4(i0, i1, i2, 0);
  knn_w[q] = make_float4(w0 * inv, w1 * inv, w2 * inv, 0.f);
}

// ---------------- gather-interpolate -> Xcat[:,256:512] ----------------
__global__ __launch_bounds__(256) void interp_kernel(
    const unsigned short* __restrict__ p2t, const int4* __restrict__ knn_i,
    const float4* __restrict__ knn_w, unsigned short* __restrict__ xcat) {
  int wid = threadIdx.x >> 6, lane = threadIdx.x & 63;
  int bn = blockIdx.x * 4 + wid;
  int b = bn >> 13;
  int4 ii = knn_i[bn];
  float4 ww = knn_w[bn];
  int d0 = lane * 4;
  const unsigned short* base = p2t + (size_t)b * S_ * 256;
  ushort4 v0 = *(const ushort4*)(base + (size_t)ii.x * 256 + d0);
  ushort4 v1 = *(const ushort4*)(base + (size_t)ii.y * 256 + d0);
  ushort4 v2 = *(const ushort4*)(base + (size_t)ii.z * 256 + d0);
  float r0 = ww.x * b2f(v0.x) + ww.y * b2f(v1.x) + ww.z * b2f(v2.x);
  float r1 = ww.x * b2f(v0.y) + ww.y * b2f(v1.y) + ww.z * b2f(v2.y);
  float r2 = ww.x * b2f(v0.z) + ww.y * b2f(v1.z) + ww.z * b2f(v2.z);
  float r3 = ww.x * b2f(v0.w) + ww.y * b2f(v1.w) + ww.z * b2f(v2.w);
  ushort4 o = make_ushort4(f2b(r0), f2b(r1), f2b(r2), f2b(r3));
  *(ushort4*)&xcat[(size_t)bn * 512 + 256 + d0] = o;
}

// ---------------- bf16 MFMA GEMM: C[M][256] = A[M][K] * Bt[256][K]^T ----------------
template <int K>
__global__ __launch_bounds__(512) void gemm_bt(
    const unsigned short* __restrict__ A, const unsigned short* __restrict__ Bt,
    unsigned short* __restrict__ C) {
  __shared__ unsigned short Alds[128 * 32];
  __shared__ unsigned short Blds[256 * 32];
  int t = threadIdx.x;
  int lane = t & 63, wid = t >> 6;
  int wr = wid >> 2, wc = wid & 3;
  size_t bm = (size_t)blockIdx.x * 128;

  f32x4 acc[4][4] = {};

  int akc = (t & 3) * 8;
  const unsigned short* aSrc = A + (bm + (t >> 2)) * K + akc;
  const unsigned short* bSrc1 = Bt + (size_t)(t >> 2) * K + akc;
  const unsigned short* bSrc2 = Bt + (size_t)((t >> 2) + 128) * K + akc;
  char* aDst = (char*)Alds + wid * 1024;
  char* bDst1 = (char*)Blds + wid * 1024;
  char* bDst2 = (char*)Blds + 8192 + wid * 1024;

  for (int kt = 0; kt < K / 32; ++kt) {
    int ko = kt * 32;
    gload_lds16(aSrc + ko, aDst);
    gload_lds16(bSrc1 + ko, bDst1);
    gload_lds16(bSrc2 + ko, bDst2);
    __syncthreads();
    bf16x8 a[4], bfr[4];
#pragma unroll
    for (int m = 0; m < 4; ++m) {
      int row = wr * 64 + m * 16 + (lane & 15);
      a[m] = *(const bf16x8*)&Alds[row * 32 + (lane >> 4) * 8];
    }
#pragma unroll
    for (int n = 0; n < 4; ++n) {
      int col = wc * 64 + n * 16 + (lane & 15);
      bfr[n] = *(const bf16x8*)&Blds[col * 32 + (lane >> 4) * 8];
    }
#pragma unroll
    for (int m = 0; m < 4; ++m)
#pragma unroll
      for (int n = 0; n < 4; ++n)
        acc[m][n] = __builtin_amdgcn_mfma_f32_16x16x32_bf16(a[m], bfr[n], acc[m][n], 0, 0, 0);
    __syncthreads();
  }

  int crow0 = wr * 64 + (lane >> 4) * 4;
  int ccol0 = wc * 64 + (lane & 15);
#pragma unroll
  for (int m = 0; m < 4; ++m)
#pragma unroll
    for (int n = 0; n < 4; ++n)
#pragma unroll
      for (int j = 0; j < 4; ++j) {
        size_t r = bm + crow0 + m * 16 + j;
        C[r * 256 + ccol0 + n * 16] = f2b(acc[m][n][j]);
      }
}

// ---------------- BN stats: partial sums per 256-row block ----------------
__global__ __launch_bounds__(256) void stats_partial(
    const unsigned short* __restrict__ Y, float* __restrict__ ps, float* __restrict__ pq) {
  int blk = blockIdx.x;
  int c = threadIdx.x;
  const unsigned short* row = Y + (size_t)blk * 256 * 256 + c;
  float s = 0.f, q = 0.f;
#pragma unroll 4
  for (int r = 0; r < 256; ++r) {
    float v = b2f(row[(size_t)r * 256]);
    s += v; q += v * v;
  }
  ps[blk * 256 + c] = s;
  pq[blk * 256 + c] = q;
}

__global__ __launch_bounds__(256) void stats_final(
    const float* __restrict__ ps, const float* __restrict__ pq,
    const float* __restrict__ g, const float* __restrict__ be,
    float* __restrict__ scale, float* __restrict__ shift) {
  int c = threadIdx.x;
  float s = 0.f, q = 0.f;
  for (int r = 0; r < 256; ++r) { s += ps[r * 256 + c]; q += pq[r * 256 + c]; }
  float mean = s * (1.0f / 65536.0f);
  float var = fmaxf(q * (1.0f / 65536.0f) - mean * mean, 0.f);
  float sc = g[c] * rsqrtf(var + 1e-5f);
  scale[c] = sc;
  shift[c] = be[c] - mean * sc;
}

// ---------------- BN apply + ReLU (elementwise, 8 bf16/thread) ----------------
__global__ __launch_bounds__(256) void bnrelu_kernel(
    const unsigned short* __restrict__ Y, const float* __restrict__ scale,
    const float* __restrict__ shift, unsigned short* __restrict__ X) {
  size_t i = ((size_t)blockIdx.x * 256 + threadIdx.x) * 8;
  int c = (int)(i & 255);
  ushort4 v0 = *(const ushort4*)&Y[i];
  ushort4 v1 = *(const ushort4*)&Y[i + 4];
  float4 s0 = *(const float4*)&scale[c];
  float4 s1 = *(const float4*)&scale[c + 4];
  float4 h0 = *(const float4*)&shift[c];
  float4 h1 = *(const float4*)&shift[c + 4];
  ushort4 o0, o1;
  o0.x = f2b(fmaxf(b2f(v0.x) * s0.x + h0.x, 0.f));
  o0.y = f2b(fmaxf(b2f(v0.y) * s0.y + h0.y, 0.f));
  o0.z = f2b(fmaxf(b2f(v0.z) * s0.z + h0.z, 0.f));
  o0.w = f2b(fmaxf(b2f(v0.w) * s0.w + h0.w, 0.f));
  o1.x = f2b(fmaxf(b2f(v1.x) * s1.x + h1.x, 0.f));
  o1.y = f2b(fmaxf(b2f(v1.y) * s1.y + h1.y, 0.f));
  o1.z = f2b(fmaxf(b2f(v1.z) * s1.z + h1.z, 0.f));
  o1.w = f2b(fmaxf(b2f(v1.w) * s1.w + h1.w, 0.f));
  *(ushort4*)&X[i] = o0;
  *(ushort4*)&X[i + 4] = o1;
}

// ------- final: BN+ReLU + transpose [bn][o] -> out f32 [B][256][N] -------
__global__ __launch_bounds__(256) void final_kernel(
    const unsigned short* __restrict__ Y1, const float* __restrict__ scale,
    const float* __restrict__ shift, float* __restrict__ out) {
  __shared__ float lds[32][65];
  int n0 = blockIdx.x * 32, o0 = blockIdx.y * 64, b = blockIdx.z;
  int t = threadIdx.x;
  int tx = t & 63, ty = t >> 6;  // ty 0..3
#pragma unroll
  for (int rr = 0; rr < 8; ++rr) {
    int nl = ty + rr * 4;
    lds[nl][tx] = b2f(Y1[((size_t)b * N_ + n0 + nl) * 256 + o0 + tx]);
  }
  __syncthreads();
  int wn = t & 31, wo = t >> 5;  // wo 0..7
#pragma unroll
  for (int it = 0; it < 8; ++it) {
    int ol = wo + it * 8;
    int o = o0 + ol;
    float v = fmaxf(lds[wn][ol] * scale[o] + shift[o], 0.f);
    out[((size_t)b * 256 + o) * N_ + n0 + wn] = v;
  }
}

// ---------------- workspace layout (bytes) ----------------
static const size_t OFF_XCAT = 0;                       // 67108864 (y1 aliases)
static const size_t OFF_P2T  = 67108864;                // 8388608
static const size_t OFF_KI   = OFF_P2T + 8388608;       // 1048576
static const size_t OFF_KW   = OFF_KI + 1048576;        // 1048576
static const size_t OFF_Y0   = OFF_KW + 1048576;        // 33554432 (Dp/Ip alias)
static const size_t OFF_X1   = OFF_Y0 + 33554432;       // 33554432 (cand aliases)
static const size_t OFF_W0B  = OFF_X1 + 33554432;       // 262144
static const size_t OFF_W1B  = OFF_W0B + 262144;        // 131072
static const size_t OFF_PS   = OFF_W1B + 131072;        // 262144
static const size_t OFF_PQ   = OFF_PS + 262144;         // 262144
static const size_t OFF_SC0  = OFF_PQ + 262144;         // 1024
static const size_t OFF_SH0  = OFF_SC0 + 1024;
static const size_t OFF_SC1  = OFF_SH0 + 1024;
static const size_t OFF_SH1  = OFF_SC1 + 1024;

extern "C" void kernel_launch(void* const* d_in, const int* in_sizes, int n_in,
                              void* d_out, int out_size, void* d_ws, size_t ws_size,
                              hipStream_t stream) {
  const float* xyz1    = (const float*)d_in[0];
  const float* xyz2    = (const float*)d_in[1];
  const float* points1 = (const float*)d_in[2];
  const float* points2 = (const float*)d_in[3];
  const float* W0      = (const float*)d_in[4];
  // d_in[5] = b0 (cancels exactly inside BatchNorm; skipped)
  const float* W1      = (const float*)d_in[6];
  // d_in[7] = b1 (cancels)
  const float* g0      = (const float*)d_in[8];
  const float* be0     = (const float*)d_in[9];
  const float* g1      = (const float*)d_in[10];
  const float* be1     = (const float*)d_in[11];

  char* ws = (char*)d_ws;
  unsigned short* xcat = (unsigned short*)(ws + OFF_XCAT);
  unsigned short* p2t  = (unsigned short*)(ws + OFF_P2T);
  int4*  ki  = (int4*)(ws + OFF_KI);
  float4* kw = (float4*)(ws + OFF_KW);
  unsigned short* y0  = (unsigned short*)(ws + OFF_Y0);
  unsigned short* x1  = (unsigned short*)(ws + OFF_X1);
  unsigned short* y1  = (unsigned short*)(ws + OFF_XCAT);  // alias: xcat dead after GEMM0
  unsigned short* w0b = (unsigned short*)(ws + OFF_W0B);
  unsigned short* w1b = (unsigned short*)(ws + OFF_W1B);
  float* ps  = (float*)(ws + OFF_PS);
  float* pq  = (float*)(ws + OFF_PQ);
  float* sc0 = (float*)(ws + OFF_SC0);
  float* sh0 = (float*)(ws + OFF_SH0);
  float* sc1 = (float*)(ws + OFF_SC1);
  float* sh1 = (float*)(ws + OFF_SH1);
  // aliases (regions dead at time of use):
  float4*  cand = (float4*)(ws + OFF_X1);                 // dead before bnrelu writes x1
  double4* Dp   = (double4*)(ws + OFF_Y0);                // dead before gemm0 writes y0
  int4*    Ip   = (int4*)(ws + OFF_Y0 + (size_t)SPLIT_ * BN_TOT * 32);

  dim3 blk(256);

  cast_f32_bf16<<<dim3(512), blk, 0, stream>>>(W0, w0b, 256 * 512);
  cast_f32_bf16<<<dim3(256), blk, 0, stream>>>(W1, w1b, 256 * 256);

  pack_cand<<<dim3(B_ * S_ / 256), blk, 0, stream>>>(xyz2, cand);
  knn_split<<<dim3(N_ / 256, B_, SPLIT_), blk, 0, stream>>>(xyz1, cand, Dp, Ip);
  knn_merge<<<dim3(BN_TOT / 256), blk, 0, stream>>>(Dp, Ip, ki, kw);

  transpose_cast<<<dim3(N_ / 32, 4, B_), blk, 0, stream>>>(points1, xcat, N_, 512);
  transpose_cast<<<dim3(S_ / 32, 4, B_), blk, 0, stream>>>(points2, p2t, S_, 256);

  interp_kernel<<<dim3(BN_TOT / 4), blk, 0, stream>>>(p2t, ki, kw, xcat);

  gemm_bt<512><<<dim3(BN_TOT / 128), dim3(512), 0, stream>>>(xcat, w0b, y0);

  stats_partial<<<dim3(256), blk, 0, stream>>>(y0, ps, pq);
  stats_final<<<dim3(1), blk, 0, stream>>>(ps, pq, g0, be0, sc0, sh0);
  bnrelu_kernel<<<dim3(BN_TOT * 256 / 8 / 256), blk, 0, stream>>>(y0, sc0, sh0, x1);

  gemm_bt<256><<<dim3(BN_TOT / 128), dim3(512), 0, stream>>>(x1, w1b, y1);

  stats_partial<<<dim3(256), blk, 0, stream>>>(y1, ps, pq);
  stats_final<<<dim3(1), blk, 0, stream>>>(ps, pq, g1, be1, sc1, sh1);

  final_kernel<<<dim3(N_ / 32, 4, B_), blk, 0, stream>>>(y1, sc1, sh1, (float*)d_out);
}